// Round 4
// baseline (109.969 us; speedup 1.0000x reference)
//
#include <hip/hip_runtime.h>
#include <hip/hip_cooperative_groups.h>
#include <math.h>

namespace cg = cooperative_groups;

#define B_ 16
#define L_ 1024
#define IMG 224
#define PIX (IMG*IMG)        /* 50176 */
#define NBD (B_*8)           /* 128 */

/* ---- workspace (float) layout — all plain stores, no atomics, no init ----
   OFF_XPMIN: x min partials[64]      OFF_XPMAX: x max partials[64]
   OFF_BDMIN: per-(b,d) pair-min[128] OFF_BDMAX: per-(b,d) pair-max[128]
   OFF_GPMIN: g min partials[256]     OFF_GPMAX: g max partials[256]
   OFF_T    : tbl[B][224][16]  (lerped c[0..7], s[0..7] at sample positions)
   OFF_G    : g[B][224][224]
*/
#define OFF_XPMIN 0
#define OFF_XPMAX 64
#define OFF_BDMIN 128
#define OFF_BDMAX 256
#define OFF_GPMIN 384
#define OFF_GPMAX 640
#define OFF_T     1024                 /* 57344 floats */
#define OFF_G     58368                /* 802816 floats */

__device__ __forceinline__ float cclip(float xn) {
    return fminf(fmaxf(xn, -1.0f + 1e-6f), 1.0f - 1e-6f);
}
__device__ __forceinline__ int bucketf(float c) {
    int k = (int)((c + 1.0f) * 512.0f);
    return min(1023, max(0, k));
}

/* block min/max -> red[0]=min, red[1]=max, visible to all threads on return */
template <int NTHR>
__device__ __forceinline__ void block_minmax_share(float mn, float mx, float* red) {
    #pragma unroll
    for (int off = 32; off > 0; off >>= 1) {
        mn = fminf(mn, __shfl_down(mn, off));
        mx = fmaxf(mx, __shfl_down(mx, off));
    }
    const int lane = threadIdx.x & 63;
    const int wave = threadIdx.x >> 6;
    if (lane == 0) { red[2 + wave*2] = mn; red[3 + wave*2] = mx; }
    __syncthreads();
    if (threadIdx.x == 0) {
        #pragma unroll
        for (int w = 1; w < NTHR/64; ++w) {
            mn = fminf(mn, red[2 + w*2]);
            mx = fmaxf(mx, red[3 + w*2]);
        }
        red[0] = mn; red[1] = mx;
    }
    __syncthreads();
}

__global__ __launch_bounds__(512) void k_all(const float* __restrict__ x,
                                             float* __restrict__ wsf,
                                             float* __restrict__ out) {
    cg::grid_group grid = cg::this_grid();
    __shared__ float red[20];
    __shared__ float corig[L_];
    __shared__ float arr[L_];
    __shared__ int   cnt[L_];          /* counts, then scatter cursors */
    __shared__ int   pref[L_ + 1];
    __shared__ float ly[224];

    const int t   = threadIdx.x;
    const int blk = blockIdx.x;

    /* ---------------- P1: global x min/max (partials) ---------------- */
    {
        float mn = 1e30f, mx = -1e30f;
        int gi = blk*512 + t;                       /* 32768 float4 total */
        if (gi < 32768) {
            float4 v = ((const float4*)x)[gi];
            mn = fminf(fminf(v.x, v.y), fminf(v.z, v.w));
            mx = fmaxf(fmaxf(v.x, v.y), fmaxf(v.z, v.w));
        }
        if (blk < 64) {
            block_minmax_share<512>(mn, mx, red);
            if (t == 0) { wsf[OFF_XPMIN + blk] = red[0]; wsf[OFF_XPMAX + blk] = red[1]; }
        }
    }
    grid.sync();

    /* -------- P2: per-(b,d) analytic pair min/max + sample table -------- */
    if (blk < NBD) {
        const int b = blk >> 3, d = blk & 7;
        /* global x min/max from 64 partials */
        float pmn = (t < 64) ? wsf[OFF_XPMIN + t] :  1e30f;
        float pmx = (t < 64) ? wsf[OFF_XPMAX + t] : -1e30f;
        block_minmax_share<512>(pmn, pmx, red);
        float lo = red[0], hi = red[1], r = hi - lo, sc, sh;
        if (r < 1e-8f) { sc = 0.0f; sh = -1.0f; }
        else           { sc = 2.0f / (r + 1e-8f); sh = -lo*sc - 1.0f; }

        /* load c row; track per-bd cmin/cmax */
        cnt[t] = 0; cnt[t + 512] = 0;
        float cmn = 1e30f, cmx = -1e30f;
        #pragma unroll
        for (int k = 0; k < 2; ++k) {
            int i = t + k*512;
            float c = cclip(x[((size_t)(b*L_ + i))*8 + d]*sc + sh);
            corig[i] = c;
            cmn = fminf(cmn, c); cmx = fmaxf(cmx, c);
        }
        block_minmax_share<512>(cmn, cmx, red);     /* also orders cnt/corig */
        float cMin = red[0], cMax = red[1];

        /* counting sort by bucket */
        #pragma unroll
        for (int k = 0; k < 2; ++k)
            atomicAdd(&cnt[bucketf(corig[t + k*512])], 1);
        __syncthreads();
        if (t < 64) {                                /* wave-0 chunk scan */
            int s = 0;
            #pragma unroll
            for (int e = 0; e < 16; ++e) s += cnt[t*16 + e];
            int v = s;
            #pragma unroll
            for (int o = 1; o < 64; o <<= 1) {
                int u = __shfl_up(v, o);
                if (t >= o) v += u;
            }
            int run = v - s;                         /* exclusive chunk prefix */
            #pragma unroll
            for (int e = 0; e < 16; ++e) { pref[t*16 + e] = run; run += cnt[t*16 + e]; }
            if (t == 63) pref[L_] = run;
        }
        __syncthreads();
        cnt[t] = pref[t]; cnt[t + 512] = pref[t + 512];   /* cursors */
        __syncthreads();
        #pragma unroll
        for (int k = 0; k < 2; ++k) {
            float c = corig[t + k*512];
            int p = atomicAdd(&cnt[bucketf(c)], 1);
            arr[p] = c;
        }
        __syncthreads();

        /* min over pairs: for each row i, candidates = contiguous span
           covering bucket(-c_i) plus nearest nonempty bucket below/above;
           every eval is an exact pair cos, so extras are harmless. */
        float rowmin = 1e30f;
        #pragma unroll
        for (int k = 0; k < 2; ++k) {
            float ci = corig[t + k*512];
            float si = sqrtf(fmaxf(1.0f - ci*ci, 0.0f));
            int kt = bucketf(-ci);
            int lo_p = pref[kt], hi_p = pref[kt + 1];
            int start = lo_p, end = hi_p;
            if (lo_p > 0)   start = pref[bucketf(arr[lo_p - 1])];
            if (hi_p < L_)  end   = pref[bucketf(arr[hi_p]) + 1];
            for (int p = start; p < end; ++p) {
                float cj = arr[p];
                float sj = sqrtf(fmaxf(1.0f - cj*cj, 0.0f));
                rowmin = fminf(rowmin, ci*cj - si*sj);
            }
        }
        block_minmax_share<512>(rowmin, -1e30f, red);
        if (t == 0) {
            wsf[OFF_BDMIN + blk] = red[0];
            wsf[OFF_BDMAX + blk] = fmaxf(2.0f*cMin*cMin - 1.0f,
                                         2.0f*cMax*cMax - 1.0f);
        }

        /* sample table d-slice: lerped (c,s) at 224 half-pixel positions */
        if (t < IMG) {
            const float SC = 1024.0f / 224.0f;
            float syf = (t + 0.5f)*SC - 0.5f;
            int i0 = (int)floorf(syf);
            i0 = max(0, min(i0, L_ - 2));
            float f = syf - (float)i0;
            float ca = corig[i0], cb = corig[i0 + 1];
            float sa = sqrtf(fmaxf(1.0f - ca*ca, 0.0f));
            float sb = sqrtf(fmaxf(1.0f - cb*cb, 0.0f));
            size_t base = OFF_T + ((size_t)(b*IMG + t))*16;
            wsf[base + d]     = ca + f*(cb - ca);
            wsf[base + 8 + d] = sa + f*(sb - sa);
        }
    }
    grid.sync();

    /* ---------------- P3: resize + g + min/max partials ---------------- */
    {
        const int b = blk >> 4, sub = blk & 15;
        const float* tb = wsf + OFF_T + (size_t)b*IMG*16;
        float a[8], bias = 0.f;
        #pragma unroll
        for (int d = 0; d < 8; ++d) {
            float plo = wsf[OFF_BDMIN + b*8 + d];
            float phi = wsf[OFF_BDMAX + b*8 + d];
            float rr  = phi - plo;
            float inv = (rr < 1e-8f) ? 0.0f : 1.0f / (rr + 1e-8f);
            a[d] = inv * 0.125f;
            bias += plo * inv * 0.125f;
        }
        if (t < 224) ly[t] = tb[(size_t)sub*224 + t];   /* 14 rows x 16 */
        __syncthreads();
        bool active = (t < 448);
        int rbit = (t >= 224) ? 1 : 0;
        int ox = min(t - rbit*224, IMG - 1);
        const float4* xt = (const float4*)(tb + (size_t)ox*16);
        float4 cx0 = xt[0], cx1 = xt[1], sx0 = xt[2], sx1 = xt[3];
        float mn = 1e30f, mx = -1e30f;
        #pragma unroll
        for (int rr2 = 0; rr2 < 7; ++rr2) {
            const float* Y = ly + (rr2*2 + rbit)*16;
            float acc;
            acc  = (a[0]*Y[0])*cx0.x - (a[0]*Y[ 8])*sx0.x;
            acc += (a[1]*Y[1])*cx0.y - (a[1]*Y[ 9])*sx0.y;
            acc += (a[2]*Y[2])*cx0.z - (a[2]*Y[10])*sx0.z;
            acc += (a[3]*Y[3])*cx0.w - (a[3]*Y[11])*sx0.w;
            acc += (a[4]*Y[4])*cx1.x - (a[4]*Y[12])*sx1.x;
            acc += (a[5]*Y[5])*cx1.y - (a[5]*Y[13])*sx1.y;
            acc += (a[6]*Y[6])*cx1.z - (a[6]*Y[14])*sx1.z;
            acc += (a[7]*Y[7])*cx1.w - (a[7]*Y[15])*sx1.w;
            float g = acc - bias;
            if (active) {
                int oy = sub*14 + rr2*2 + rbit;
                wsf[OFF_G + ((size_t)(b*IMG + oy))*IMG + ox] = g;
                mn = fminf(mn, g);
                mx = fmaxf(mx, g);
            }
        }
        block_minmax_share<512>(mn, mx, red);
        if (t == 0) { wsf[OFF_GPMIN + blk] = red[0]; wsf[OFF_GPMAX + blk] = red[1]; }
    }
    grid.sync();

    /* ---------------- P4: global normalize + 3-channel write ---------------- */
    {
        float pmn = (t < 256) ? wsf[OFF_GPMIN + t] :  1e30f;
        float pmx = (t < 256) ? wsf[OFF_GPMAX + t] : -1e30f;
        block_minmax_share<512>(pmn, pmx, red);
        float gmin = red[0];
        float scale = 1.0f / ((red[1] - gmin) + 1e-6f);
        const float4* gsrc = (const float4*)(wsf + OFF_G);
        for (int idx = blk*512 + t; idx < B_*PIX/4; idx += 256*512) {
            float4 gv = gsrc[idx];
            float4 v;
            v.x = (gv.x - gmin)*scale;
            v.y = (gv.y - gmin)*scale;
            v.z = (gv.z - gmin)*scale;
            v.w = (gv.w - gmin)*scale;
            int b   = idx / (PIX/4);
            int rem = idx - b*(PIX/4);
            float4* ob = (float4*)(out + (size_t)b*3*PIX) + rem;
            ob[0]         = v;
            ob[PIX/4]     = v;
            ob[2*(PIX/4)] = v;
        }
    }
}

extern "C" void kernel_launch(void* const* d_in, const int* in_sizes, int n_in,
                              void* d_out, int out_size, void* d_ws, size_t ws_size,
                              hipStream_t stream) {
    const float* x = (const float*)d_in[0];
    float* out     = (float*)d_out;
    float* wsf     = (float*)d_ws;
    void* args[] = { (void*)&x, (void*)&wsf, (void*)&out };
    hipLaunchCooperativeKernel((const void*)k_all, dim3(256), dim3(512),
                               args, 0, stream);
}

// Round 5
// 28.196 us; speedup vs baseline: 3.9002x; 3.9002x over previous
//
#include <hip/hip_runtime.h>
#include <math.h>

#define B_ 16
#define L_ 1024
#define IMG 224
#define PIX (IMG*IMG)        /* 50176 */
#define NBD 128

/* ---- workspace (float) layout — plain stores only, no atomics, no init ----
   OFF_A    : a[128]    = inv/8 per (b,d)
   OFF_TERM : term[128] = lo*inv/8 per (b,d)
   OFF_GPMIN: g min partials[512]   OFF_GPMAX: g max partials[512]
   OFF_T    : tbl[B][224][16]  (lerped c[0..7], s[0..7] at sample positions)
   OFF_G    : g[B][224][224]
*/
#define OFF_A     0
#define OFF_TERM  128
#define OFF_GPMIN 256
#define OFF_GPMAX 768
#define OFF_T     1280                 /* 57344 floats */
#define OFF_G     58624                /* 802816 floats */

__device__ __forceinline__ float cclip(float xn) {
    return fminf(fmaxf(xn, -1.0f + 1e-6f), 1.0f - 1e-6f);
}
__device__ __forceinline__ int bucketf(float c) {
    int k = (int)((c + 1.0f) * 512.0f);
    return min(1023, max(0, k));
}

/* block min/max -> red[0]=min, red[1]=max, visible to all threads on return */
template <int NTHR>
__device__ __forceinline__ void block_minmax_share(float mn, float mx, float* red) {
    #pragma unroll
    for (int off = 32; off > 0; off >>= 1) {
        mn = fminf(mn, __shfl_down(mn, off));
        mx = fmaxf(mx, __shfl_down(mx, off));
    }
    const int lane = threadIdx.x & 63;
    const int wave = threadIdx.x >> 6;
    if (lane == 0) { red[2 + wave*2] = mn; red[3 + wave*2] = mx; }
    __syncthreads();
    if (threadIdx.x == 0) {
        #pragma unroll
        for (int w = 1; w < NTHR/64; ++w) {
            mn = fminf(mn, red[2 + w*2]);
            mx = fmaxf(mx, red[3 + w*2]);
        }
        red[0] = mn; red[1] = mx;
    }
    __syncthreads();
}

/* K1: one block per (b,d).
   (a) global x min/max computed redundantly per block (x is L2-resident;
       min/max is associative+commutative -> identical result in every block)
   (b) bucket counting-sort of the c-row; analytic pair min/max:
         max = max(2*cmin^2-1, 2*cmax^2-1)
         min = min over i of exact cos at the c-neighbors of -c_i
             (span = target bucket + nearest nonempty bucket each side;
              every eval is a real pair, extras harmless)
   (c) a[bd], term[bd]; (d) d-slice of the (c,s) sample table. */
__global__ __launch_bounds__(512) void k_bd(const float* __restrict__ x,
                                            float* __restrict__ wsf) {
    __shared__ float red[20];
    __shared__ float corig[L_];
    __shared__ float arr[L_];
    __shared__ int   cnt[1024];        /* counts, then scatter cursors */
    __shared__ int   pref[1025];
    const int bd = blockIdx.x;
    const int b = bd >> 3, d = bd & 7;
    const int t = threadIdx.x;

    /* (a) global x min/max */
    float mn = 1e30f, mx = -1e30f;
    const float4* xv = (const float4*)x;
    #pragma unroll 4
    for (int i = t; i < 32768; i += 512) {
        float4 v = xv[i];
        mn = fminf(mn, fminf(fminf(v.x, v.y), fminf(v.z, v.w)));
        mx = fmaxf(mx, fmaxf(fmaxf(v.x, v.y), fmaxf(v.z, v.w)));
    }
    block_minmax_share<512>(mn, mx, red);
    float lo = red[0], hi = red[1], r = hi - lo, sc, sh;
    if (r < 1e-8f) { sc = 0.0f; sh = -1.0f; }
    else           { sc = 2.0f / (r + 1e-8f); sh = -lo*sc - 1.0f; }

    /* (b) load c row, per-bd cmin/cmax; zero counts */
    cnt[t] = 0; cnt[t + 512] = 0;
    float cmn = 1e30f, cmx = -1e30f;
    #pragma unroll
    for (int k = 0; k < 2; ++k) {
        int i = t + k*512;
        float c = cclip(x[((size_t)(b*L_ + i))*8 + d]*sc + sh);
        corig[i] = c;
        cmn = fminf(cmn, c); cmx = fmaxf(cmx, c);
    }
    block_minmax_share<512>(cmn, cmx, red);   /* syncs also order cnt/corig */
    float cMin = red[0], cMax = red[1];

    /* counting sort by bucket */
    #pragma unroll
    for (int k = 0; k < 2; ++k)
        atomicAdd(&cnt[bucketf(corig[t + k*512])], 1);
    __syncthreads();
    if (t < 64) {                              /* wave-0 chunked scan */
        int s = 0;
        #pragma unroll
        for (int e = 0; e < 16; ++e) s += cnt[t*16 + e];
        int v = s;
        #pragma unroll
        for (int o = 1; o < 64; o <<= 1) {
            int u = __shfl_up(v, o);
            if (t >= o) v += u;
        }
        int run = v - s;                       /* exclusive chunk prefix */
        #pragma unroll
        for (int e = 0; e < 16; ++e) { pref[t*16 + e] = run; run += cnt[t*16 + e]; }
        if (t == 63) pref[L_] = run;
    }
    __syncthreads();
    cnt[t] = pref[t]; cnt[t + 512] = pref[t + 512];    /* cursors */
    __syncthreads();
    #pragma unroll
    for (int k = 0; k < 2; ++k) {
        float c = corig[t + k*512];
        int p = atomicAdd(&cnt[bucketf(c)], 1);
        arr[p] = c;
    }
    __syncthreads();

    /* pair-min via neighbor span of -c_i */
    float rowmin = 1e30f;
    #pragma unroll
    for (int k = 0; k < 2; ++k) {
        float ci = corig[t + k*512];
        float si = sqrtf(fmaxf(1.0f - ci*ci, 0.0f));
        int kt = bucketf(-ci);
        int lo_p = pref[kt], hi_p = pref[kt + 1];
        int start = lo_p, end = hi_p;
        if (lo_p > 0)   start = pref[bucketf(arr[lo_p - 1])];
        if (hi_p < L_)  end   = pref[bucketf(arr[hi_p]) + 1];
        for (int p = start; p < end; ++p) {
            float cj = arr[p];
            float sj = sqrtf(fmaxf(1.0f - cj*cj, 0.0f));
            rowmin = fminf(rowmin, ci*cj - si*sj);
        }
    }
    block_minmax_share<512>(rowmin, -1e30f, red);
    if (t == 0) {
        float plo = red[0];
        float phi = fmaxf(2.0f*cMin*cMin - 1.0f, 2.0f*cMax*cMax - 1.0f);
        float rr  = phi - plo;
        float inv = (rr < 1e-8f) ? 0.0f : 1.0f / (rr + 1e-8f);
        wsf[OFF_A + bd]    = inv * 0.125f;
        wsf[OFF_TERM + bd] = plo * inv * 0.125f;
    }

    /* (d) sample table d-slice: lerped (c,s) at 224 half-pixel positions */
    if (t < IMG) {
        const float SC = 1024.0f / 224.0f;
        float syf = (t + 0.5f)*SC - 0.5f;
        int i0 = (int)floorf(syf);
        i0 = max(0, min(i0, L_ - 2));
        float f = syf - (float)i0;
        float ca = corig[i0], cb = corig[i0 + 1];
        float sa = sqrtf(fmaxf(1.0f - ca*ca, 0.0f));
        float sb = sqrtf(fmaxf(1.0f - cb*cb, 0.0f));
        size_t base = OFF_T + ((size_t)(b*IMG + t))*16;
        wsf[base + d]     = ca + f*(cb - ca);
        wsf[base + 8 + d] = sa + f*(sb - sa);
    }
}

/* K2: resize. 512 blocks = 16 b x 32 strips of 7 rows; thread = ox.
   x-side (c,s) coalesced from table, y-side via 112-float LDS strip.
   g min/max per block -> plain-store partials. */
__global__ __launch_bounds__(256) void k_resize(float* __restrict__ wsf) {
    __shared__ float lds_y[112];
    __shared__ float red[16];
    int b     = blockIdx.x >> 5;
    int strip = blockIdx.x & 31;
    const float* tb = wsf + OFF_T + (size_t)b*IMG*16;
    int t = threadIdx.x;
    if (t < 112) lds_y[t] = tb[strip*112 + t];
    __syncthreads();
    int ox = min(t, IMG-1);
    bool active = (t < IMG);
    const float4* xt = (const float4*)(tb + (size_t)ox*16);
    float4 cx0 = xt[0], cx1 = xt[1], sx0 = xt[2], sx1 = xt[3];
    const float4* av = (const float4*)(wsf + OFF_A + b*8);
    float4 a0 = av[0], a1 = av[1];
    float bias = 0.f;
    #pragma unroll
    for (int dd = 0; dd < 8; ++dd) bias += wsf[OFF_TERM + b*8 + dd];
    float mn = 1e30f, mx = -1e30f;
    #pragma unroll
    for (int rr = 0; rr < 7; ++rr) {
        const float* Y = lds_y + rr*16;
        float acc;
        acc  = (a0.x*Y[0])*cx0.x - (a0.x*Y[ 8])*sx0.x;
        acc += (a0.y*Y[1])*cx0.y - (a0.y*Y[ 9])*sx0.y;
        acc += (a0.z*Y[2])*cx0.z - (a0.z*Y[10])*sx0.z;
        acc += (a0.w*Y[3])*cx0.w - (a0.w*Y[11])*sx0.w;
        acc += (a1.x*Y[4])*cx1.x - (a1.x*Y[12])*sx1.x;
        acc += (a1.y*Y[5])*cx1.y - (a1.y*Y[13])*sx1.y;
        acc += (a1.z*Y[6])*cx1.z - (a1.z*Y[14])*sx1.z;
        acc += (a1.w*Y[7])*cx1.w - (a1.w*Y[15])*sx1.w;
        float g = acc - bias;
        if (active) {
            int oy = strip*7 + rr;
            wsf[OFF_G + ((size_t)(b*IMG + oy))*IMG + ox] = g;
            mn = fminf(mn, g);
            mx = fmaxf(mx, g);
        }
    }
    block_minmax_share<256>(mn, mx, red);
    if (t == 0) {
        wsf[OFF_GPMIN + blockIdx.x] = red[0];
        wsf[OFF_GPMAX + blockIdx.x] = red[1];
    }
}

/* K3: reduce 512 g-partials per block, normalize, 3-channel float4 write */
__global__ __launch_bounds__(256) void k_out(const float* __restrict__ wsf,
                                             float* __restrict__ out) {
    __shared__ float red[16];
    int t = threadIdx.x;
    float pmn = fminf(wsf[OFF_GPMIN + t], wsf[OFF_GPMIN + t + 256]);
    float pmx = fmaxf(wsf[OFF_GPMAX + t], wsf[OFF_GPMAX + t + 256]);
    block_minmax_share<256>(pmn, pmx, red);
    float gmin = red[0];
    float scale = 1.0f / ((red[1] - gmin) + 1e-6f);
    int idx = blockIdx.x*256 + t;                /* [0, 200704) float4 groups */
    float4 gv = ((const float4*)(wsf + OFF_G))[idx];
    float4 v;
    v.x = (gv.x - gmin)*scale;
    v.y = (gv.y - gmin)*scale;
    v.z = (gv.z - gmin)*scale;
    v.w = (gv.w - gmin)*scale;
    int b   = idx / (PIX/4);
    int rem = idx - b*(PIX/4);
    float4* ob = (float4*)(out + (size_t)b*3*PIX) + rem;
    ob[0]         = v;
    ob[PIX/4]     = v;
    ob[2*(PIX/4)] = v;
}

extern "C" void kernel_launch(void* const* d_in, const int* in_sizes, int n_in,
                              void* d_out, int out_size, void* d_ws, size_t ws_size,
                              hipStream_t stream) {
    const float* x = (const float*)d_in[0];
    float* out     = (float*)d_out;
    float* wsf     = (float*)d_ws;

    k_bd    <<<NBD,            512, 0, stream>>>(x, wsf);
    k_resize<<<512,            256, 0, stream>>>(wsf);
    k_out   <<<(B_*PIX/4)/256, 256, 0, stream>>>(wsf, out);
}